// Round 8
// baseline (391.454 us; speedup 1.0000x reference)
//
#include <hip/hip_runtime.h>
#include <hip/hip_bf16.h>

#define HW    4096
#define CDIM  512
#define CHALF 256
#define NB    4
#define FLASH_LDS 99328
#define MERGE_LDS 66048

using bf16 = __hip_bfloat16;
typedef __attribute__((ext_vector_type(8))) short short8;
typedef __attribute__((ext_vector_type(4))) float float4v;

typedef __attribute__((address_space(1))) void gvoid_t;
typedef __attribute__((address_space(3))) void svoid_t;
#define GLD16(gp, lp) \
    __builtin_amdgcn_global_load_lds((gvoid_t*)(gp), (svoid_t*)(lp), 16, 0, 0)
#define MFMA(a, b, c) __builtin_amdgcn_mfma_f32_16x16x32_bf16(a, b, c, 0, 0, 0)

static __device__ __forceinline__ short8 ld_short8(const bf16* p) {
    return *reinterpret_cast<const short8*>(p);
}
static __device__ __forceinline__ float b2f(short s) {
    unsigned u = ((unsigned)(unsigned short)s) << 16;
    return __builtin_bit_cast(float, u);
}
static __device__ __forceinline__ short f2bs(float f) {
    bf16 h = __float2bfloat16(f);
    return __builtin_bit_cast(short, h);
}

// ---------------------------------------------------------------------------
// Transpose + cast: Fc[b][c][p] fp32 -> FcT[b][p][c] bf16 (and Fs -> FsT)
// ---------------------------------------------------------------------------
__global__ void transpose_cast(const float* __restrict__ Fc,
                               const float* __restrict__ Fs,
                               bf16* __restrict__ FcT, bf16* __restrict__ FsT) {
    __shared__ float tile[32][33];
    int p0 = blockIdx.x * 32, c0 = blockIdx.y * 32;
    int z = blockIdx.z;
    int b = z & 3, which = z >> 2;
    const float* src = (which ? Fs : Fc) + (size_t)b * CDIM * HW;
    bf16* dst = (which ? FsT : FcT) + (size_t)b * HW * CDIM;
    int tx = threadIdx.x, ty = threadIdx.y;  // (32,8)
    for (int i = 0; i < 4; i++)
        tile[ty + 8 * i][tx] = src[(size_t)(c0 + ty + 8 * i) * HW + p0 + tx];
    __syncthreads();
    for (int i = 0; i < 4; i++)
        dst[(size_t)(p0 + ty + 8 * i) * CDIM + c0 + tx] =
            __float2bfloat16(tile[tx][ty + 8 * i]);
}

// All four weight casts in one launch; dst regions contiguous from fw.
__global__ void cast4(const float* __restrict__ fw, const float* __restrict__ gw,
                      const float* __restrict__ hw, const float* __restrict__ ow,
                      bf16* __restrict__ dst) {
    int i = blockIdx.x * 256 + threadIdx.x;
    float v;
    if (i < 131072)       v = fw[i] * 0.0625f;
    else if (i < 262144)  v = gw[i - 131072];
    else if (i < 524288)  v = hw[i - 262144];
    else                  v = ow[i - 524288];
    dst[i] = __float2bfloat16(v);
}

// ---------------------------------------------------------------------------
// Fused f+g conv GEMM: D[m][n] = sum_k Act[m][k]*W[n][k] + bias[n]
// 128x128 tile, BK=64, double-buffered LDS, 1 barrier/K-step.
// Flat grid, XCD-grouped.
// ---------------------------------------------------------------------------
__launch_bounds__(256, 2)
__global__ void gemm_fg(const bf16* __restrict__ A1, const bf16* __restrict__ A2,
                        size_t sA,
                        const bf16* __restrict__ W1, const bf16* __restrict__ W2,
                        const float* __restrict__ b1, const float* __restrict__ b2,
                        float bs1, float bs2,
                        bf16* __restrict__ D1, bf16* __restrict__ D2, size_t sD,
                        int zhalf, int N, int K) {
    __shared__ bf16 Asf[2][8192];
    __shared__ bf16 Bsf[2][8192];
    int lid = blockIdx.x;
    int xcd = lid & 7, idx = lid >> 3;
    int bx = idx & 1;
    int yzg = xcd * 32 + (idx >> 1);     // 0..255
    int z = yzg >> 5;                    // 0..7
    int by = yzg & 31;
    const bf16 *A, *W; const float* bias; float bsc; bf16* D;
    if (z < zhalf) { A = A1 + sA * z;           W = W1; bias = b1; bsc = bs1; D = D1 + sD * z; }
    else           { A = A2 + sA * (z - zhalf); W = W2; bias = b2; bsc = bs2; D = D2 + sD * (z - zhalf); }
    int m0 = by * 128, n0 = bx * 128;
    int t = threadIdx.x;
    int w = t >> 6, lane = t & 63;
    int wm = w >> 1, wn = w & 1;
    int l15 = lane & 15, quad = lane >> 4;
    int lr = lane >> 3, lc = (lane & 7) ^ lr;
    int nk = K >> 6;
    float4v acc[4][4] = {};

    for (int q = 0; q < 4; q++) {
        int rb = w * 32 + q * 8;
        GLD16(A + (size_t)(m0 + rb + lr) * K + lc * 8, &Asf[0][rb * 64]);
        GLD16(W + (size_t)(n0 + rb + lr) * K + lc * 8, &Bsf[0][rb * 64]);
    }
    for (int i = 0; i < nk; i++) {
        __syncthreads();
        if (i + 1 < nk) {
            int k0 = (i + 1) << 6, nb = (i + 1) & 1;
            for (int q = 0; q < 4; q++) {
                int rb = w * 32 + q * 8;
                GLD16(A + (size_t)(m0 + rb + lr) * K + k0 + lc * 8, &Asf[nb][rb * 64]);
                GLD16(W + (size_t)(n0 + rb + lr) * K + k0 + lc * 8, &Bsf[nb][rb * 64]);
            }
        }
        int cb = i & 1;
        for (int h = 0; h < 2; h++) {
            int p = (h * 4 + quad) ^ (l15 & 7);
            short8 af[4], bfr[4];
            for (int sm = 0; sm < 4; sm++)
                af[sm] = *(const short8*)&Asf[cb][(wm * 64 + sm * 16 + l15) * 64 + p * 8];
            for (int sn = 0; sn < 4; sn++)
                bfr[sn] = *(const short8*)&Bsf[cb][(wn * 64 + sn * 16 + l15) * 64 + p * 8];
            for (int sm = 0; sm < 4; sm++)
                for (int sn = 0; sn < 4; sn++)
                    acc[sm][sn] = MFMA(af[sm], bfr[sn], acc[sm][sn]);
        }
    }
    for (int sm = 0; sm < 4; sm++)
        for (int sn = 0; sn < 4; sn++) {
            int n = n0 + wn * 64 + sn * 16 + l15;
            for (int r = 0; r < 4; r++) {
                int m = m0 + wm * 64 + sm * 16 + quad * 4 + r;
                D[(size_t)m * N + n] = __float2bfloat16(acc[sm][sn][r] + bias[n] * bsc);
            }
        }
}

// ---------------------------------------------------------------------------
// Fh GEMM: D[m][n] = sum_k h_w[m][k]*FsT[z][n][k] + bias[m], bf16 out.
// Flat grid, XCD-grouped: all 4 m-tiles of one (n,z) on one XCD.
// ---------------------------------------------------------------------------
__launch_bounds__(256, 2)
__global__ void gemm_bw(const bf16* __restrict__ Aw,
                        const bf16* __restrict__ Bact, size_t sB,
                        const float* __restrict__ bias,
                        bf16* __restrict__ Dp, size_t sD,
                        int N, int K) {
    __shared__ bf16 Asf[2][8192];
    __shared__ bf16 Bsf[2][8192];
    int lid = blockIdx.x;
    int xcd = lid & 7, idx = lid >> 3;
    int my = idx & 3;
    int nzg = xcd * 16 + (idx >> 2);     // 0..127
    int z = nzg >> 5;                    // 0..3
    int nx = nzg & 31;
    const bf16* A = Aw;
    const bf16* Bm = Bact + sB * z;
    int m0 = my * 128, n0 = nx * 128;
    int t = threadIdx.x;
    int w = t >> 6, lane = t & 63;
    int wm = w >> 1, wn = w & 1;
    int l15 = lane & 15, quad = lane >> 4;
    int lr = lane >> 3, lc = (lane & 7) ^ lr;
    int nk = K >> 6;
    float4v acc[4][4] = {};

    for (int q = 0; q < 4; q++) {
        int rb = w * 32 + q * 8;
        GLD16(A + (size_t)(m0 + rb + lr) * K + lc * 8, &Asf[0][rb * 64]);
        GLD16(Bm + (size_t)(n0 + rb + lr) * K + lc * 8, &Bsf[0][rb * 64]);
    }
    for (int i = 0; i < nk; i++) {
        __syncthreads();
        if (i + 1 < nk) {
            int k0 = (i + 1) << 6, nb = (i + 1) & 1;
            for (int q = 0; q < 4; q++) {
                int rb = w * 32 + q * 8;
                GLD16(A + (size_t)(m0 + rb + lr) * K + k0 + lc * 8, &Asf[nb][rb * 64]);
                GLD16(Bm + (size_t)(n0 + rb + lr) * K + k0 + lc * 8, &Bsf[nb][rb * 64]);
            }
        }
        int cb = i & 1;
        for (int h = 0; h < 2; h++) {
            int p = (h * 4 + quad) ^ (l15 & 7);
            short8 af[4], bfr[4];
            for (int sm = 0; sm < 4; sm++)
                af[sm] = *(const short8*)&Asf[cb][(wm * 64 + sm * 16 + l15) * 64 + p * 8];
            for (int sn = 0; sn < 4; sn++)
                bfr[sn] = *(const short8*)&Bsf[cb][(wn * 64 + sn * 16 + l15) * 64 + p * 8];
            for (int sm = 0; sm < 4; sm++)
                for (int sn = 0; sn < 4; sn++)
                    acc[sm][sn] = MFMA(af[sm], bfr[sn], acc[sm][sn]);
        }
    }
    for (int sm = 0; sm < 4; sm++)
        for (int sn = 0; sn < 4; sn++) {
            int n = n0 + wn * 64 + sn * 16 + l15;
            for (int r = 0; r < 4; r++) {
                int m = m0 + wm * 64 + sm * 16 + quad * 4 + r;
                Dp[sD * z + (size_t)m * N + n] =
                    __float2bfloat16(acc[sm][sn][r] + bias[m]);
            }
        }
}

// ---------------------------------------------------------------------------
// Flash attention v15 = v10 + PHASE SKEW: waves 0-3 run PV(t-1) then QK(t);
// waves 4-7 run QK(t) then PV(t-1). Legal because QK(t) and PV(t-1) have no
// intra-phase dependency (P double-buffered: QK writes Ps[kb], PV reads
// Ps[pb=kb^1]; K buf kb drained at the previous barrier; K-DMA overwrite
// safety depends only on the barrier). SIMD i hosts waves i and i+4 ->
// the two resident waves anti-align: one wave's softmax/VALU overlaps the
// other's MFMA cluster. All else byte-identical to the 191 us v10/v14.
// ---------------------------------------------------------------------------
__launch_bounds__(512, 1)
__global__ void flash_attn(const bf16* __restrict__ Q_, const bf16* __restrict__ Kt_,
                           const bf16* __restrict__ V_,
                           bf16* __restrict__ O0_, bf16* __restrict__ O1_,
                           float* __restrict__ L0_, float* __restrict__ L1_) {
    extern __shared__ char smem[];
    bf16* Ksf = (bf16*)smem;                 // [2][64][256] swizzled, 64 KB
    short* Ps = (short*)(smem + 65536);      // [2][128][64] rotated, 32 KB
    float* lpart = (float*)(smem + 98304);   // [2][128]

    int lid = blockIdx.x;
    int stream = lid & 7;                    // XCD-pinned (b, jh) stream
    int b = stream & 3, jh = stream >> 2;
    int i0 = (lid >> 3) * 128;
    const bf16* Kt = Kt_ + (size_t)b * HW * CHALF;
    const bf16* V  = V_ + (size_t)b * CDIM * HW;
    bf16* Out   = (jh ? O1_ : O0_) + ((size_t)b * HW + i0) * CDIM;
    float* Lout = (jh ? L1_ : L0_) + (size_t)b * HW + i0;

    int t = threadIdx.x;
    int w = t >> 6, lane = t & 63;
    int l15 = lane & 15, quad = lane >> 4;
    int rm   = (w & 3) * 32;                 // QK row base (32 rows)
    int cnw  = (w >> 2) * 32;                // QK col base (32 cols)
    int chb  = (w >> 2) * 4;                 // P chunk base for writes
    int c0w  = w * 64;                       // PV channel slice
    int jbeg = jh * (HW / 2), jend = jbeg + HW / 2;

    // Q fragments in registers: rows rm+l15 and rm+16+l15, all K=256
    short8 qf0[8], qf1[8];
    {
        const bf16* qp = Q_ + ((size_t)b * HW + i0 + rm + l15) * CHALF + quad * 8;
        #pragma unroll
        for (int k8 = 0; k8 < 8; k8++) {
            qf0[k8] = ld_short8(qp + k8 * 32);
            qf1[k8] = ld_short8(qp + 16 * CHALF + k8 * 32);
        }
    }
    int r0 = lane >> 5, cc = lane & 31;      // K-DMA lane mapping

    // K-DMA(0) -> buf0
    for (int i = 0; i < 4; i++) {
        int rp = i * 8 + w;
        int r = 2 * rp + r0;
        int c = cc ^ (r & 7);
        GLD16(Kt + (size_t)(jbeg + r) * CHALF + c * 8, &Ksf[rp * 512]);
    }
    float l_lane[2][4] = {};
    float4v oacc[8][4] = {};
    asm volatile("s_waitcnt vmcnt(0)" ::: "memory");
    __builtin_amdgcn_s_barrier();

    const bf16* vp = V + (size_t)(c0w + l15) * HW + quad * 8;
    short8 va[4];

    // QK(t) from Ksf buf kb + softmax -> Ps buf kb
    auto qksm = [&](int kb) {
        const bf16* Kb = Ksf + kb * 16384;
        short* Pb = Ps + kb * 8192;
        float4v s00 = {}, s01 = {}, s10 = {}, s11 = {};
        __builtin_amdgcn_s_setprio(1);
        #pragma unroll
        for (int k8 = 0; k8 < 8; k8++) {
            int pq = ((k8 * 4 + quad) ^ (l15 & 7)) * 8;
            short8 k0 = *(const short8*)&Kb[(cnw + l15) * 256 + pq];
            short8 k1 = *(const short8*)&Kb[(cnw + 16 + l15) * 256 + pq];
            s00 = MFMA(qf0[k8], k0, s00);
            s01 = MFMA(qf0[k8], k1, s01);
            s10 = MFMA(qf1[k8], k0, s10);
            s11 = MFMA(qf1[k8], k1, s11);
        }
        __builtin_amdgcn_s_setprio(0);
        #pragma unroll
        for (int r = 0; r < 4; r++) {
            int rl0 = rm + quad * 4 + r, rl1 = rl0 + 16;
            int cw = chb + (l15 >> 3);
            float p00 = __expf(s00[r]);
            float p01 = __expf(s01[r]);
            float p10 = __expf(s10[r]);
            float p11 = __expf(s11[r]);
            l_lane[0][r] += p00 + p01;
            l_lane[1][r] += p10 + p11;
            Pb[rl0 * 64 + ((cw + rl0) & 7) * 8 + (l15 & 7)]     = f2bs(p00);
            Pb[rl0 * 64 + ((cw + 2 + rl0) & 7) * 8 + (l15 & 7)] = f2bs(p01);
            Pb[rl1 * 64 + ((cw + rl1) & 7) * 8 + (l15 & 7)]     = f2bs(p10);
            Pb[rl1 * 64 + ((cw + 2 + rl1) & 7) * 8 + (l15 & 7)] = f2bs(p11);
        }
    };
    // PV half: P buf pb, chunk offset coff (0: va-half, 4: vb-half)
    auto pvhalf = [&](int pb, int coff, const short8* vv) {
        __builtin_amdgcn_s_setprio(1);
        #pragma unroll
        for (int sm = 0; sm < 8; sm++) {
            int rl = sm * 16 + l15;
            short8 pf = *(const short8*)&Ps[pb * 8192 + rl * 64 +
                                            ((coff + quad + rl) & 7) * 8];
            #pragma unroll
            for (int sn = 0; sn < 4; sn++)
                oacc[sm][sn] = MFMA(pf, vv[sn], oacc[sm][sn]);
        }
        __builtin_amdgcn_s_setprio(0);
    };

    // ---- pre-phase (t=0): K-DMA(1) -> buf1, va(0), QK(0)+softmax(0)
    for (int i = 0; i < 4; i++) {
        int rp = i * 8 + w;
        int r = 2 * rp + r0;
        int c = cc ^ (r & 7);
        GLD16(Kt + (size_t)(jbeg + 64 + r) * CHALF + c * 8,
              &Ksf[16384 + rp * 512]);
    }
    #pragma unroll
    for (int sn = 0; sn < 4; sn++)
        va[sn] = ld_short8(vp + jbeg + (size_t)(sn * 16) * HW);
    qksm(0);
    asm volatile("s_waitcnt lgkmcnt(0)" ::: "memory");
    asm volatile("s_waitcnt vmcnt(4)" ::: "memory");
    __builtin_amdgcn_s_barrier();

    // ---- main phases t = 1..31: {PV(t-1), QK(t)} in wave-group order,
    // one barrier each
    for (int it = 1; it < 32; it++) {
        int j0 = jbeg + it * 64, jp = j0 - 64;
        int pb = (it - 1) & 1, kb = it & 1;
        // vb(t-1) loads (consumed by PV-b this phase)
        short8 vb[4];
        #pragma unroll
        for (int sn = 0; sn < 4; sn++)
            vb[sn] = ld_short8(vp + jp + 32 + (size_t)(sn * 16) * HW);
        // K-DMA(t+1) -> other K buffer (issued BEFORE va so vmcnt(4) covers it)
        if (it < 31) {
            for (int i = 0; i < 4; i++) {
                int rp = i * 8 + w;
                int r = 2 * rp + r0;
                int c = cc ^ (r & 7);
                GLD16(Kt + (size_t)(j0 + 64 + r) * CHALF + c * 8,
                      &Ksf[(kb ^ 1) * 16384 + rp * 512]);
            }
        }
        if ((w >> 2) == 0) {
            // group A: PV(t-1) then QK(t)
            pvhalf(pb, 0, va);
            __builtin_amdgcn_sched_barrier(0);   // pin va(t) loads below PV-a
            #pragma unroll
            for (int sn = 0; sn < 4; sn++)
                va[sn] = ld_short8(vp + j0 + (size_t)(sn * 16) * HW);
            pvhalf(pb, 4, vb);
            qksm(kb);
        } else {
            // group B: QK(t) first — anti-aligned with group A on each SIMD
            qksm(kb);
            pvhalf(pb, 0, va);
            __builtin_amdgcn_sched_barrier(0);   // pin va(t) loads below PV-a
            #pragma unroll
            for (int sn = 0; sn < 4; sn++)
                va[sn] = ld_short8(vp + j0 + (size_t)(sn * 16) * HW);
            pvhalf(pb, 4, vb);
        }
        // single barrier: P visible (lgkmcnt 0), K-DMA drained (vmcnt 4 —
        // the 4 va loads may stay in flight), then converge.
        asm volatile("s_waitcnt lgkmcnt(0)" ::: "memory");
        asm volatile("s_waitcnt vmcnt(4)" ::: "memory");
        __builtin_amdgcn_s_barrier();
    }

    // ---- epilogue phase: PV(31) from Ps[1]
    {
        short8 vb[4];
        int jp = jend - 64;
        #pragma unroll
        for (int sn = 0; sn < 4; sn++)
            vb[sn] = ld_short8(vp + jp + 32 + (size_t)(sn * 16) * HW);
        pvhalf(1, 0, va);
        pvhalf(1, 4, vb);
    }

    // epilogue: combine l partials across the two col-half wave groups
    #pragma unroll
    for (int ms = 0; ms < 2; ms++)
        for (int r = 0; r < 4; r++) {
            float red = l_lane[ms][r];
            red += __shfl_xor(red, 1);
            red += __shfl_xor(red, 2);
            red += __shfl_xor(red, 4);
            red += __shfl_xor(red, 8);
            if (l15 == 0)
                lpart[(w >> 2) * 128 + rm + ms * 16 + quad * 4 + r] = red;
        }
    __syncthreads();
    if ((w >> 2) == 0 && l15 == 0)
        for (int ms = 0; ms < 2; ms++)
            for (int r = 0; r < 4; r++) {
                int rl = rm + ms * 16 + quad * 4 + r;
                Lout[rl] = lpart[rl] + lpart[128 + rl];
            }
    for (int sm = 0; sm < 8; sm++)
        for (int r = 0; r < 4; r++) {
            int rl = sm * 16 + quad * 4 + r;
            float li = 1.0f / (lpart[rl] + lpart[128 + rl]);
            for (int sn = 0; sn < 4; sn++)
                Out[(size_t)rl * CDIM + c0w + sn * 16 + l15] =
                    __float2bfloat16(oacc[sm][sn][r] * li);
        }
}

// ---------------------------------------------------------------------------
// Fused merge + out-conv v3 (proven in R7): 256 blocks x 64 i-rows, 66 KB
// LDS, 512 threads (8 waves/CU), wave co-slice 64.
// ---------------------------------------------------------------------------
__launch_bounds__(512, 1)
__global__ void merge_out(const bf16* __restrict__ Op0, const bf16* __restrict__ Op1,
                          const float* __restrict__ L0, const float* __restrict__ L1,
                          const bf16* __restrict__ ow, const float* __restrict__ out_b,
                          const float* __restrict__ Fc, float* __restrict__ out) {
    extern __shared__ char smem[];
    short* Os = (short*)smem;               // [64][512] swizzled, 64 KB (bits)
    float* lw = (float*)(smem + 65536);     // [64][2]

    int rt = blockIdx.x;                    // 0..255
    int b = rt >> 6;
    int i0 = (rt & 63) * 64;
    size_t obase = ((size_t)b * HW + i0) * CDIM;
    int t = threadIdx.x;

    if (t < 64) {
        float l0 = L0[(size_t)b * HW + i0 + t];
        float l1 = L1[(size_t)b * HW + i0 + t];
        float inv = 1.f / (l0 + l1);
        lw[t * 2] = l0 * inv;
        lw[t * 2 + 1] = l1 * inv;
    }
    __syncthreads();

    // merge into LDS, chunk-swizzled pos = cc ^ (row & 7); 8 iters @ 512 thr
    for (int q = 0; q < 8; q++) {
        int idx = q * 512 + t;
        int row = idx >> 6, cc = idx & 63;
        short8 a = ld_short8(Op0 + obase + (size_t)row * CDIM + cc * 8);
        short8 c = ld_short8(Op1 + obase + (size_t)row * CDIM + cc * 8);
        float w0 = lw[row * 2], w1 = lw[row * 2 + 1];
        short8 o;
        #pragma unroll
        for (int j = 0; j < 8; j++)
            o[j] = f2bs(w0 * b2f(a[j]) + w1 * b2f(c[j]));
        *(short8*)&Os[row * 512 + (cc ^ (row & 7)) * 8] = o;
    }
    __syncthreads();

    // GEMM: M=512 (co, wave slice 64), N=64 (i), K=512
    int w = t >> 6, lane = t & 63;
    int l15 = lane & 15, quad = lane >> 4;
    int m0 = w * 64;
    float4v acc[4][4] = {};
    for (int k8 = 0; k8 < 16; k8++) {
        short8 bfr[4];
        #pragma unroll
        for (int n16 = 0; n16 < 4; n16++)
            bfr[n16] = *(const short8*)&Os[(n16 * 16 + l15) * 512 +
                (((k8 * 4 + quad) ^ (l15 & 7))) * 8];
        short8 af[4];
        #pragma unroll
        for (int m16 = 0; m16 < 4; m16++)
            af[m16] = ld_short8(ow + (size_t)(m0 + m16 * 16 + l15) * CDIM +
                                k8 * 32 + quad * 8);
        #pragma unroll
        for (int m16 = 0; m16 < 4; m16++)
            for (int n16 = 0; n16 < 4; n16++)
                acc[m16][n16] = MFMA(af[m16], bfr[n16], acc[m16][n16]);
    }

    const float* fcb = Fc + (size_t)b * CDIM * HW;
    float* outb = out + (size_t)b * CDIM * HW;
    for (int m16 = 0; m16 < 4; m16++)
        for (int r = 0; r < 4; r++) {
            int co = m0 + m16 * 16 + quad * 4 + r;
            float bb = out_b[co];
            for (int n16 = 0; n16 < 4; n16++) {
                int i = i0 + n16 * 16 + l15;
                outb[(size_t)co * HW + i] =
                    acc[m16][n16][r] + bb + fcb[(size_t)co * HW + i];
            }
        }
}

// ---------------------------------------------------------------------------
extern "C" void kernel_launch(void* const* d_in, const int* in_sizes, int n_in,
                              void* d_out, int out_size, void* d_ws, size_t ws_size,
                              hipStream_t stream) {
    const float* Fc   = (const float*)d_in[0];
    const float* Fs   = (const float*)d_in[1];
    const float* f_w  = (const float*)d_in[2];
    const float* f_b  = (const float*)d_in[3];
    const float* g_w  = (const float*)d_in[4];
    const float* g_b  = (const float*)d_in[5];
    const float* h_w  = (const float*)d_in[6];
    const float* h_b  = (const float*)d_in[7];
    const float* out_w = (const float*)d_in[8];
    const float* out_b = (const float*)d_in[9];
    float* out = (float*)d_out;

    bf16* FcT = (bf16*)d_ws;                          // [B][4096][512]; later Op0
    bf16* FsT = FcT + (size_t)NB * HW * CDIM;         // [B][4096][512]; later Op1
    bf16* FfT = FsT + (size_t)NB * HW * CDIM;         // [B][4096][256]
    bf16* FgT = FfT + (size_t)NB * HW * CHALF;        // [B][4096][256]
    bf16* Fh  = FgT + (size_t)NB * HW * CHALF;        // [B][512][4096]
    bf16* fw  = Fh  + (size_t)NB * CDIM * HW;
    bf16* gw  = fw + (size_t)CHALF * CDIM;
    bf16* hw  = gw + (size_t)CHALF * CDIM;
    bf16* ow  = hw + (size_t)CDIM * CDIM;
    float* L0 = (float*)(ow + (size_t)CDIM * CDIM);
    float* L1 = L0 + (size_t)NB * HW;
    bf16* Op0 = FcT;
    bf16* Op1 = FsT;

    hipFuncSetAttribute((const void*)flash_attn,
                        hipFuncAttributeMaxDynamicSharedMemorySize, FLASH_LDS);
    hipFuncSetAttribute((const void*)merge_out,
                        hipFuncAttributeMaxDynamicSharedMemorySize, MERGE_LDS);

    transpose_cast<<<dim3(HW / 32, CDIM / 32, NB * 2), dim3(32, 8), 0, stream>>>(
        Fc, Fs, FcT, FsT);
    cast4<<<dim3(786432 / 256), 256, 0, stream>>>(f_w, g_w, h_w, out_w, fw);

    // fused f+g: z<4 -> Ff from FcT/fw, z>=4 -> Fg from FsT/gw (flat grid)
    gemm_fg<<<dim3(512), 256, 0, stream>>>(
        FcT, FsT, (size_t)HW * CDIM, fw, gw, f_b, g_b, 0.0625f, 1.0f,
        FfT, FgT, (size_t)HW * CHALF, NB, CHALF, CDIM);
    // Fh[o][p] = h_w x FsT  (M=512, N=4096, K=512), flat grid
    gemm_bw<<<dim3(512), 256, 0, stream>>>(
        hw, FsT, (size_t)HW * CDIM, h_b, Fh, (size_t)CDIM * HW, HW, CDIM);
    // flash attention v15: 256 blocks (1/CU), BM=128, 8 waves, split-j,
    // K+P double-buffered, single barrier per iteration, phase-skewed waves
    flash_attn<<<dim3(256), 512, FLASH_LDS, stream>>>(
        FfT, FgT, Fh, Op0, Op1, L0, L1);
    // fused merge + out conv (+ residual), fp32 out: 256 blocks, 512 thr
    merge_out<<<dim3(256), 512, MERGE_LDS, stream>>>(
        Op0, Op1, L0, L1, ow, out_b, Fc, out);
}

// Round 9
// 363.073 us; speedup vs baseline: 1.0782x; 1.0782x over previous
//
#include <hip/hip_runtime.h>
#include <hip/hip_bf16.h>

#define HW    4096
#define CDIM  512
#define CHALF 256
#define NB    4
#define FLASH_LDS 99328
#define MERGE_LDS 66048

using bf16 = __hip_bfloat16;
typedef __attribute__((ext_vector_type(8))) short short8;
typedef __attribute__((ext_vector_type(4))) short short4v;
typedef __attribute__((ext_vector_type(4))) float float4v;

typedef __attribute__((address_space(1))) void gvoid_t;
typedef __attribute__((address_space(3))) void svoid_t;
#define GLD16(gp, lp) \
    __builtin_amdgcn_global_load_lds((gvoid_t*)(gp), (svoid_t*)(lp), 16, 0, 0)
#define MFMA(a, b, c) __builtin_amdgcn_mfma_f32_16x16x32_bf16(a, b, c, 0, 0, 0)

static __device__ __forceinline__ short8 ld_short8(const bf16* p) {
    return *reinterpret_cast<const short8*>(p);
}
static __device__ __forceinline__ float b2f(short s) {
    unsigned u = ((unsigned)(unsigned short)s) << 16;
    return __builtin_bit_cast(float, u);
}
static __device__ __forceinline__ short f2bs(float f) {
    bf16 h = __float2bfloat16(f);
    return __builtin_bit_cast(short, h);
}

// ---------------------------------------------------------------------------
// Transpose + cast v2: Fc[b][c][p] fp32 -> FcT[b][p][c] bf16 (and Fs->FsT).
// 64x64 tile, 256 threads, float4 (16B) loads, bf16x4 (8B) stores
// (the v1 kernel used scalar 4B loads / 2B stores -- G13).
// LDS fp32 [64][65]: row writes 2-way aliased (free), column reads
// stride-65 = conflict-free.
// ---------------------------------------------------------------------------
__global__ void transpose_cast(const float* __restrict__ Fc,
                               const float* __restrict__ Fs,
                               bf16* __restrict__ FcT, bf16* __restrict__ FsT) {
    __shared__ float tile[64][65];
    int p0 = blockIdx.x * 64, c0 = blockIdx.y * 64;
    int z = blockIdx.z;
    int b = z & 3, which = z >> 2;
    const float* src = (which ? Fs : Fc) + (size_t)b * CDIM * HW;
    bf16* dst = (which ? FsT : FcT) + (size_t)b * HW * CDIM;
    int t = threadIdx.x;                     // 256

    // load: 64 c-rows x 16 float4 (64 p) per row
    #pragma unroll
    for (int it = 0; it < 4; it++) {
        int idx = it * 256 + t;
        int cr = idx >> 4, pc = idx & 15;
        float4v v = *reinterpret_cast<const float4v*>(
            &src[(size_t)(c0 + cr) * HW + p0 + pc * 4]);
        tile[cr][pc * 4 + 0] = v[0];
        tile[cr][pc * 4 + 1] = v[1];
        tile[cr][pc * 4 + 2] = v[2];
        tile[cr][pc * 4 + 3] = v[3];
    }
    __syncthreads();

    // store: 64 p-rows x 16 bf16x4 (64 c) per row
    #pragma unroll
    for (int it = 0; it < 4; it++) {
        int idx = it * 256 + t;
        int pr = idx >> 4, cc = idx & 15;
        short4v o;
        o[0] = f2bs(tile[cc * 4 + 0][pr]);
        o[1] = f2bs(tile[cc * 4 + 1][pr]);
        o[2] = f2bs(tile[cc * 4 + 2][pr]);
        o[3] = f2bs(tile[cc * 4 + 3][pr]);
        *reinterpret_cast<short4v*>(
            &dst[(size_t)(p0 + pr) * CDIM + c0 + cc * 4]) = o;
    }
}

// All four weight casts in one launch; dst regions contiguous from fw.
__global__ void cast4(const float* __restrict__ fw, const float* __restrict__ gw,
                      const float* __restrict__ hw, const float* __restrict__ ow,
                      bf16* __restrict__ dst) {
    int i = blockIdx.x * 256 + threadIdx.x;
    float v;
    if (i < 131072)       v = fw[i] * 0.0625f;
    else if (i < 262144)  v = gw[i - 131072];
    else if (i < 524288)  v = hw[i - 262144];
    else                  v = ow[i - 524288];
    dst[i] = __float2bfloat16(v);
}

// ---------------------------------------------------------------------------
// Fused f+g conv GEMM: D[m][n] = sum_k Act[m][k]*W[n][k] + bias[n]
// 128x128 tile, BK=64, double-buffered LDS, 1 barrier/K-step.
// Flat grid, XCD-grouped.
// ---------------------------------------------------------------------------
__launch_bounds__(256, 2)
__global__ void gemm_fg(const bf16* __restrict__ A1, const bf16* __restrict__ A2,
                        size_t sA,
                        const bf16* __restrict__ W1, const bf16* __restrict__ W2,
                        const float* __restrict__ b1, const float* __restrict__ b2,
                        float bs1, float bs2,
                        bf16* __restrict__ D1, bf16* __restrict__ D2, size_t sD,
                        int zhalf, int N, int K) {
    __shared__ bf16 Asf[2][8192];
    __shared__ bf16 Bsf[2][8192];
    int lid = blockIdx.x;
    int xcd = lid & 7, idx = lid >> 3;
    int bx = idx & 1;
    int yzg = xcd * 32 + (idx >> 1);     // 0..255
    int z = yzg >> 5;                    // 0..7
    int by = yzg & 31;
    const bf16 *A, *W; const float* bias; float bsc; bf16* D;
    if (z < zhalf) { A = A1 + sA * z;           W = W1; bias = b1; bsc = bs1; D = D1 + sD * z; }
    else           { A = A2 + sA * (z - zhalf); W = W2; bias = b2; bsc = bs2; D = D2 + sD * (z - zhalf); }
    int m0 = by * 128, n0 = bx * 128;
    int t = threadIdx.x;
    int w = t >> 6, lane = t & 63;
    int wm = w >> 1, wn = w & 1;
    int l15 = lane & 15, quad = lane >> 4;
    int lr = lane >> 3, lc = (lane & 7) ^ lr;
    int nk = K >> 6;
    float4v acc[4][4] = {};

    for (int q = 0; q < 4; q++) {
        int rb = w * 32 + q * 8;
        GLD16(A + (size_t)(m0 + rb + lr) * K + lc * 8, &Asf[0][rb * 64]);
        GLD16(W + (size_t)(n0 + rb + lr) * K + lc * 8, &Bsf[0][rb * 64]);
    }
    for (int i = 0; i < nk; i++) {
        __syncthreads();
        if (i + 1 < nk) {
            int k0 = (i + 1) << 6, nb = (i + 1) & 1;
            for (int q = 0; q < 4; q++) {
                int rb = w * 32 + q * 8;
                GLD16(A + (size_t)(m0 + rb + lr) * K + k0 + lc * 8, &Asf[nb][rb * 64]);
                GLD16(W + (size_t)(n0 + rb + lr) * K + k0 + lc * 8, &Bsf[nb][rb * 64]);
            }
        }
        int cb = i & 1;
        for (int h = 0; h < 2; h++) {
            int p = (h * 4 + quad) ^ (l15 & 7);
            short8 af[4], bfr[4];
            for (int sm = 0; sm < 4; sm++)
                af[sm] = *(const short8*)&Asf[cb][(wm * 64 + sm * 16 + l15) * 64 + p * 8];
            for (int sn = 0; sn < 4; sn++)
                bfr[sn] = *(const short8*)&Bsf[cb][(wn * 64 + sn * 16 + l15) * 64 + p * 8];
            for (int sm = 0; sm < 4; sm++)
                for (int sn = 0; sn < 4; sn++)
                    acc[sm][sn] = MFMA(af[sm], bfr[sn], acc[sm][sn]);
        }
    }
    for (int sm = 0; sm < 4; sm++)
        for (int sn = 0; sn < 4; sn++) {
            int n = n0 + wn * 64 + sn * 16 + l15;
            for (int r = 0; r < 4; r++) {
                int m = m0 + wm * 64 + sm * 16 + quad * 4 + r;
                D[(size_t)m * N + n] = __float2bfloat16(acc[sm][sn][r] + bias[n] * bsc);
            }
        }
}

// ---------------------------------------------------------------------------
// Fh GEMM: D[m][n] = sum_k h_w[m][k]*FsT[z][n][k] + bias[m], bf16 out.
// Flat grid, XCD-grouped: all 4 m-tiles of one (n,z) on one XCD.
// ---------------------------------------------------------------------------
__launch_bounds__(256, 2)
__global__ void gemm_bw(const bf16* __restrict__ Aw,
                        const bf16* __restrict__ Bact, size_t sB,
                        const float* __restrict__ bias,
                        bf16* __restrict__ Dp, size_t sD,
                        int N, int K) {
    __shared__ bf16 Asf[2][8192];
    __shared__ bf16 Bsf[2][8192];
    int lid = blockIdx.x;
    int xcd = lid & 7, idx = lid >> 3;
    int my = idx & 3;
    int nzg = xcd * 16 + (idx >> 2);     // 0..127
    int z = nzg >> 5;                    // 0..3
    int nx = nzg & 31;
    const bf16* A = Aw;
    const bf16* Bm = Bact + sB * z;
    int m0 = my * 128, n0 = nx * 128;
    int t = threadIdx.x;
    int w = t >> 6, lane = t & 63;
    int wm = w >> 1, wn = w & 1;
    int l15 = lane & 15, quad = lane >> 4;
    int lr = lane >> 3, lc = (lane & 7) ^ lr;
    int nk = K >> 6;
    float4v acc[4][4] = {};

    for (int q = 0; q < 4; q++) {
        int rb = w * 32 + q * 8;
        GLD16(A + (size_t)(m0 + rb + lr) * K + lc * 8, &Asf[0][rb * 64]);
        GLD16(Bm + (size_t)(n0 + rb + lr) * K + lc * 8, &Bsf[0][rb * 64]);
    }
    for (int i = 0; i < nk; i++) {
        __syncthreads();
        if (i + 1 < nk) {
            int k0 = (i + 1) << 6, nb = (i + 1) & 1;
            for (int q = 0; q < 4; q++) {
                int rb = w * 32 + q * 8;
                GLD16(A + (size_t)(m0 + rb + lr) * K + k0 + lc * 8, &Asf[nb][rb * 64]);
                GLD16(Bm + (size_t)(n0 + rb + lr) * K + k0 + lc * 8, &Bsf[nb][rb * 64]);
            }
        }
        int cb = i & 1;
        for (int h = 0; h < 2; h++) {
            int p = (h * 4 + quad) ^ (l15 & 7);
            short8 af[4], bfr[4];
            for (int sm = 0; sm < 4; sm++)
                af[sm] = *(const short8*)&Asf[cb][(wm * 64 + sm * 16 + l15) * 64 + p * 8];
            for (int sn = 0; sn < 4; sn++)
                bfr[sn] = *(const short8*)&Bsf[cb][(wn * 64 + sn * 16 + l15) * 64 + p * 8];
            for (int sm = 0; sm < 4; sm++)
                for (int sn = 0; sn < 4; sn++)
                    acc[sm][sn] = MFMA(af[sm], bfr[sn], acc[sm][sn]);
        }
    }
    for (int sm = 0; sm < 4; sm++)
        for (int sn = 0; sn < 4; sn++) {
            int n = n0 + wn * 64 + sn * 16 + l15;
            for (int r = 0; r < 4; r++) {
                int m = m0 + wm * 64 + sm * 16 + quad * 4 + r;
                Dp[sD * z + (size_t)m * N + n] =
                    __float2bfloat16(acc[sm][sn][r] + bias[m]);
            }
        }
}

// ---------------------------------------------------------------------------
// Flash attention v10 (VERBATIM best): BM=128, 8 waves, 256 blocks, 1/CU;
// single barrier per iteration; K+P double-buffered; counted vmcnt(4).
// ---------------------------------------------------------------------------
__launch_bounds__(512, 1)
__global__ void flash_attn(const bf16* __restrict__ Q_, const bf16* __restrict__ Kt_,
                           const bf16* __restrict__ V_,
                           bf16* __restrict__ O0_, bf16* __restrict__ O1_,
                           float* __restrict__ L0_, float* __restrict__ L1_) {
    extern __shared__ char smem[];
    bf16* Ksf = (bf16*)smem;                 // [2][64][256] swizzled, 64 KB
    short* Ps = (short*)(smem + 65536);      // [2][128][64] rotated, 32 KB
    float* lpart = (float*)(smem + 98304);   // [2][128]

    int lid = blockIdx.x;
    int stream = lid & 7;                    // XCD-pinned (b, jh) stream
    int b = stream & 3, jh = stream >> 2;
    int i0 = (lid >> 3) * 128;
    const bf16* Kt = Kt_ + (size_t)b * HW * CHALF;
    const bf16* V  = V_ + (size_t)b * CDIM * HW;
    bf16* Out   = (jh ? O1_ : O0_) + ((size_t)b * HW + i0) * CDIM;
    float* Lout = (jh ? L1_ : L0_) + (size_t)b * HW + i0;

    int t = threadIdx.x;
    int w = t >> 6, lane = t & 63;
    int l15 = lane & 15, quad = lane >> 4;
    int rm   = (w & 3) * 32;                 // QK row base (32 rows)
    int cnw  = (w >> 2) * 32;                // QK col base (32 cols)
    int chb  = (w >> 2) * 4;                 // P chunk base for writes
    int c0w  = w * 64;                       // PV channel slice
    int jbeg = jh * (HW / 2), jend = jbeg + HW / 2;

    // Q fragments in registers: rows rm+l15 and rm+16+l15, all K=256
    short8 qf0[8], qf1[8];
    {
        const bf16* qp = Q_ + ((size_t)b * HW + i0 + rm + l15) * CHALF + quad * 8;
        #pragma unroll
        for (int k8 = 0; k8 < 8; k8++) {
            qf0[k8] = ld_short8(qp + k8 * 32);
            qf1[k8] = ld_short8(qp + 16 * CHALF + k8 * 32);
        }
    }
    int r0 = lane >> 5, cc = lane & 31;      // K-DMA lane mapping

    // K-DMA(0) -> buf0
    for (int i = 0; i < 4; i++) {
        int rp = i * 8 + w;
        int r = 2 * rp + r0;
        int c = cc ^ (r & 7);
        GLD16(Kt + (size_t)(jbeg + r) * CHALF + c * 8, &Ksf[rp * 512]);
    }
    float l_lane[2][4] = {};
    float4v oacc[8][4] = {};
    asm volatile("s_waitcnt vmcnt(0)" ::: "memory");
    __builtin_amdgcn_s_barrier();

    const bf16* vp = V + (size_t)(c0w + l15) * HW + quad * 8;
    short8 va[4];

    // QK(t) from Ksf buf kb + softmax -> Ps buf kb
    auto qksm = [&](int kb) {
        const bf16* Kb = Ksf + kb * 16384;
        short* Pb = Ps + kb * 8192;
        float4v s00 = {}, s01 = {}, s10 = {}, s11 = {};
        __builtin_amdgcn_s_setprio(1);
        #pragma unroll
        for (int k8 = 0; k8 < 8; k8++) {
            int pq = ((k8 * 4 + quad) ^ (l15 & 7)) * 8;
            short8 k0 = *(const short8*)&Kb[(cnw + l15) * 256 + pq];
            short8 k1 = *(const short8*)&Kb[(cnw + 16 + l15) * 256 + pq];
            s00 = MFMA(qf0[k8], k0, s00);
            s01 = MFMA(qf0[k8], k1, s01);
            s10 = MFMA(qf1[k8], k0, s10);
            s11 = MFMA(qf1[k8], k1, s11);
        }
        __builtin_amdgcn_s_setprio(0);
        #pragma unroll
        for (int r = 0; r < 4; r++) {
            int rl0 = rm + quad * 4 + r, rl1 = rl0 + 16;
            int cw = chb + (l15 >> 3);
            float p00 = __expf(s00[r]);
            float p01 = __expf(s01[r]);
            float p10 = __expf(s10[r]);
            float p11 = __expf(s11[r]);
            l_lane[0][r] += p00 + p01;
            l_lane[1][r] += p10 + p11;
            Pb[rl0 * 64 + ((cw + rl0) & 7) * 8 + (l15 & 7)]     = f2bs(p00);
            Pb[rl0 * 64 + ((cw + 2 + rl0) & 7) * 8 + (l15 & 7)] = f2bs(p01);
            Pb[rl1 * 64 + ((cw + rl1) & 7) * 8 + (l15 & 7)]     = f2bs(p10);
            Pb[rl1 * 64 + ((cw + 2 + rl1) & 7) * 8 + (l15 & 7)] = f2bs(p11);
        }
    };
    // PV half: P buf pb, chunk offset coff (0: va-half, 4: vb-half)
    auto pvhalf = [&](int pb, int coff, const short8* vv) {
        __builtin_amdgcn_s_setprio(1);
        #pragma unroll
        for (int sm = 0; sm < 8; sm++) {
            int rl = sm * 16 + l15;
            short8 pf = *(const short8*)&Ps[pb * 8192 + rl * 64 +
                                            ((coff + quad + rl) & 7) * 8];
            #pragma unroll
            for (int sn = 0; sn < 4; sn++)
                oacc[sm][sn] = MFMA(pf, vv[sn], oacc[sm][sn]);
        }
        __builtin_amdgcn_s_setprio(0);
    };

    // ---- pre-phase (t=0): K-DMA(1) -> buf1, va(0), QK(0)+softmax(0)
    for (int i = 0; i < 4; i++) {
        int rp = i * 8 + w;
        int r = 2 * rp + r0;
        int c = cc ^ (r & 7);
        GLD16(Kt + (size_t)(jbeg + 64 + r) * CHALF + c * 8,
              &Ksf[16384 + rp * 512]);
    }
    #pragma unroll
    for (int sn = 0; sn < 4; sn++)
        va[sn] = ld_short8(vp + jbeg + (size_t)(sn * 16) * HW);
    qksm(0);
    asm volatile("s_waitcnt lgkmcnt(0)" ::: "memory");
    asm volatile("s_waitcnt vmcnt(4)" ::: "memory");
    __builtin_amdgcn_s_barrier();

    // ---- main phases t = 1..31: PV(t-1) || QK(t), one barrier each
    for (int it = 1; it < 32; it++) {
        int j0 = jbeg + it * 64, jp = j0 - 64;
        int pb = (it - 1) & 1, kb = it & 1;
        // vb(t-1) loads (consumed by PV-b this phase)
        short8 vb[4];
        #pragma unroll
        for (int sn = 0; sn < 4; sn++)
            vb[sn] = ld_short8(vp + jp + 32 + (size_t)(sn * 16) * HW);
        // K-DMA(t+1) -> other K buffer (issued BEFORE va so vmcnt(4) covers it)
        if (it < 31) {
            for (int i = 0; i < 4; i++) {
                int rp = i * 8 + w;
                int r = 2 * rp + r0;
                int c = cc ^ (r & 7);
                GLD16(Kt + (size_t)(j0 + 64 + r) * CHALF + c * 8,
                      &Ksf[(kb ^ 1) * 16384 + rp * 512]);
            }
        }
        // PV(t-1) first half — consumes va(t-1), freeing those registers
        pvhalf(pb, 0, va);
        __builtin_amdgcn_sched_barrier(0);   // pin va(t) loads below PV-a
        // va(t) loads — held across the barrier, consumed next phase
        #pragma unroll
        for (int sn = 0; sn < 4; sn++)
            va[sn] = ld_short8(vp + j0 + (size_t)(sn * 16) * HW);
        // PV(t-1) second half
        pvhalf(pb, 4, vb);
        // QK(t) + softmax(t) -> Ps[kb]
        qksm(kb);
        // single barrier: P visible (lgkmcnt 0), K-DMA drained (vmcnt 4 —
        // the 4 va loads may stay in flight), then converge.
        asm volatile("s_waitcnt lgkmcnt(0)" ::: "memory");
        asm volatile("s_waitcnt vmcnt(4)" ::: "memory");
        __builtin_amdgcn_s_barrier();
    }

    // ---- epilogue phase: PV(31) from Ps[1]
    {
        short8 vb[4];
        int jp = jend - 64;
        #pragma unroll
        for (int sn = 0; sn < 4; sn++)
            vb[sn] = ld_short8(vp + jp + 32 + (size_t)(sn * 16) * HW);
        pvhalf(1, 0, va);
        pvhalf(1, 4, vb);
    }

    // epilogue: combine l partials across the two col-half wave groups
    #pragma unroll
    for (int ms = 0; ms < 2; ms++)
        for (int r = 0; r < 4; r++) {
            float red = l_lane[ms][r];
            red += __shfl_xor(red, 1);
            red += __shfl_xor(red, 2);
            red += __shfl_xor(red, 4);
            red += __shfl_xor(red, 8);
            if (l15 == 0)
                lpart[(w >> 2) * 128 + rm + ms * 16 + quad * 4 + r] = red;
        }
    __syncthreads();
    if ((w >> 2) == 0 && l15 == 0)
        for (int ms = 0; ms < 2; ms++)
            for (int r = 0; r < 4; r++) {
                int rl = rm + ms * 16 + quad * 4 + r;
                Lout[rl] = lpart[rl] + lpart[128 + rl];
            }
    for (int sm = 0; sm < 8; sm++)
        for (int r = 0; r < 4; r++) {
            int rl = sm * 16 + quad * 4 + r;
            float li = 1.0f / (lpart[rl] + lpart[128 + rl]);
            for (int sn = 0; sn < 4; sn++)
                Out[(size_t)rl * CDIM + c0w + sn * 16 + l15] =
                    __float2bfloat16(oacc[sm][sn][r] * li);
        }
}

// ---------------------------------------------------------------------------
// Fused merge + out-conv v3 (proven in R7): 256 blocks x 64 i-rows, 66 KB
// LDS, 512 threads (8 waves/CU), wave co-slice 64.
// ---------------------------------------------------------------------------
__launch_bounds__(512, 1)
__global__ void merge_out(const bf16* __restrict__ Op0, const bf16* __restrict__ Op1,
                          const float* __restrict__ L0, const float* __restrict__ L1,
                          const bf16* __restrict__ ow, const float* __restrict__ out_b,
                          const float* __restrict__ Fc, float* __restrict__ out) {
    extern __shared__ char smem[];
    short* Os = (short*)smem;               // [64][512] swizzled, 64 KB (bits)
    float* lw = (float*)(smem + 65536);     // [64][2]

    int rt = blockIdx.x;                    // 0..255
    int b = rt >> 6;
    int i0 = (rt & 63) * 64;
    size_t obase = ((size_t)b * HW + i0) * CDIM;
    int t = threadIdx.x;

    if (t < 64) {
        float l0 = L0[(size_t)b * HW + i0 + t];
        float l1 = L1[(size_t)b * HW + i0 + t];
        float inv = 1.f / (l0 + l1);
        lw[t * 2] = l0 * inv;
        lw[t * 2 + 1] = l1 * inv;
    }
    __syncthreads();

    // merge into LDS, chunk-swizzled pos = cc ^ (row & 7); 8 iters @ 512 thr
    for (int q = 0; q < 8; q++) {
        int idx = q * 512 + t;
        int row = idx >> 6, cc = idx & 63;
        short8 a = ld_short8(Op0 + obase + (size_t)row * CDIM + cc * 8);
        short8 c = ld_short8(Op1 + obase + (size_t)row * CDIM + cc * 8);
        float w0 = lw[row * 2], w1 = lw[row * 2 + 1];
        short8 o;
        #pragma unroll
        for (int j = 0; j < 8; j++)
            o[j] = f2bs(w0 * b2f(a[j]) + w1 * b2f(c[j]));
        *(short8*)&Os[row * 512 + (cc ^ (row & 7)) * 8] = o;
    }
    __syncthreads();

    // GEMM: M=512 (co, wave slice 64), N=64 (i), K=512
    int w = t >> 6, lane = t & 63;
    int l15 = lane & 15, quad = lane >> 4;
    int m0 = w * 64;
    float4v acc[4][4] = {};
    for (int k8 = 0; k8 < 16; k8++) {
        short8 bfr[4];
        #pragma unroll
        for (int n16 = 0; n16 < 4; n16++)
            bfr[n16] = *(const short8*)&Os[(n16 * 16 + l15) * 512 +
                (((k8 * 4 + quad) ^ (l15 & 7))) * 8];
        short8 af[4];
        #pragma unroll
        for (int m16 = 0; m16 < 4; m16++)
            af[m16] = ld_short8(ow + (size_t)(m0 + m16 * 16 + l15) * CDIM +
                                k8 * 32 + quad * 8);
        #pragma unroll
        for (int m16 = 0; m16 < 4; m16++)
            for (int n16 = 0; n16 < 4; n16++)
                acc[m16][n16] = MFMA(af[m16], bfr[n16], acc[m16][n16]);
    }

    const float* fcb = Fc + (size_t)b * CDIM * HW;
    float* outb = out + (size_t)b * CDIM * HW;
    for (int m16 = 0; m16 < 4; m16++)
        for (int r = 0; r < 4; r++) {
            int co = m0 + m16 * 16 + quad * 4 + r;
            float bb = out_b[co];
            for (int n16 = 0; n16 < 4; n16++) {
                int i = i0 + n16 * 16 + l15;
                outb[(size_t)co * HW + i] =
                    acc[m16][n16][r] + bb + fcb[(size_t)co * HW + i];
            }
        }
}

// ---------------------------------------------------------------------------
extern "C" void kernel_launch(void* const* d_in, const int* in_sizes, int n_in,
                              void* d_out, int out_size, void* d_ws, size_t ws_size,
                              hipStream_t stream) {
    const float* Fc   = (const float*)d_in[0];
    const float* Fs   = (const float*)d_in[1];
    const float* f_w  = (const float*)d_in[2];
    const float* f_b  = (const float*)d_in[3];
    const float* g_w  = (const float*)d_in[4];
    const float* g_b  = (const float*)d_in[5];
    const float* h_w  = (const float*)d_in[6];
    const float* h_b  = (const float*)d_in[7];
    const float* out_w = (const float*)d_in[8];
    const float* out_b = (const float*)d_in[9];
    float* out = (float*)d_out;

    bf16* FcT = (bf16*)d_ws;                          // [B][4096][512]; later Op0
    bf16* FsT = FcT + (size_t)NB * HW * CDIM;         // [B][4096][512]; later Op1
    bf16* FfT = FsT + (size_t)NB * HW * CDIM;         // [B][4096][256]
    bf16* FgT = FfT + (size_t)NB * HW * CHALF;        // [B][4096][256]
    bf16* Fh  = FgT + (size_t)NB * HW * CHALF;        // [B][512][4096]
    bf16* fw  = Fh  + (size_t)NB * CDIM * HW;
    bf16* gw  = fw + (size_t)CHALF * CDIM;
    bf16* hw  = gw + (size_t)CHALF * CDIM;
    bf16* ow  = hw + (size_t)CDIM * CDIM;
    float* L0 = (float*)(ow + (size_t)CDIM * CDIM);
    float* L1 = L0 + (size_t)NB * HW;
    bf16* Op0 = FcT;
    bf16* Op1 = FsT;

    hipFuncSetAttribute((const void*)flash_attn,
                        hipFuncAttributeMaxDynamicSharedMemorySize, FLASH_LDS);
    hipFuncSetAttribute((const void*)merge_out,
                        hipFuncAttributeMaxDynamicSharedMemorySize, MERGE_LDS);

    transpose_cast<<<dim3(HW / 64, CDIM / 64, NB * 2), 256, 0, stream>>>(
        Fc, Fs, FcT, FsT);
    cast4<<<dim3(786432 / 256), 256, 0, stream>>>(f_w, g_w, h_w, out_w, fw);

    // fused f+g: z<4 -> Ff from FcT/fw, z>=4 -> Fg from FsT/gw (flat grid)
    gemm_fg<<<dim3(512), 256, 0, stream>>>(
        FcT, FsT, (size_t)HW * CDIM, fw, gw, f_b, g_b, 0.0625f, 1.0f,
        FfT, FgT, (size_t)HW * CHALF, NB, CHALF, CDIM);
    // Fh[o][p] = h_w x FsT  (M=512, N=4096, K=512), flat grid
    gemm_bw<<<dim3(512), 256, 0, stream>>>(
        hw, FsT, (size_t)HW * CDIM, h_b, Fh, (size_t)CDIM * HW, HW, CDIM);
    // flash attention v10: 256 blocks (1/CU), BM=128, 8 waves, split-j,
    // K+P double-buffered, single barrier per iteration
    flash_attn<<<dim3(256), 512, FLASH_LDS, stream>>>(
        FfT, FgT, Fh, Op0, Op1, L0, L1);
    // fused merge + out conv (+ residual), fp32 out: 256 blocks, 512 thr
    merge_out<<<dim3(256), 512, MERGE_LDS, stream>>>(
        Op0, Op1, L0, L1, ow, out_b, Fc, out);
}